// Round 3
// baseline (16877.788 us; speedup 1.0000x reference)
//
#include <hip/hip_runtime.h>
#include <hip/hip_bf16.h>

#define SEQ   512
#define BATCH 64
#define INF   512
#define H     1024
#define G4H   4096

#define NBLK    128         // persistent blocks, 1/CU (LDS-bound), co-resident via coop launch
#define NCOL    8           // hidden columns per block
#define WROWS   32          // 4 gates * NCOL weight rows per block
#define WPITCH  1544        // 1536 + 8 bf16 pad (rows 16B-aligned)
#define FSTRIDE 32          // ints between per-block flags (128B: one cache line each)

typedef short  short8  __attribute__((ext_vector_type(8)));
typedef float  float4v __attribute__((ext_vector_type(4)));

// ---------------- conversion / init kernels ----------------

__global__ void f32_to_bf16_k(const float* __restrict__ src,
                              __hip_bfloat16* __restrict__ dst, int n) {
    int i = blockIdx.x * blockDim.x + threadIdx.x;
    int stride = gridDim.x * blockDim.x;
    for (; i < n; i += stride) dst[i] = __float2bfloat16(src[i]);
}

__global__ void init_h_k(const float* __restrict__ h0, __hip_bfloat16* __restrict__ hb,
                         int* __restrict__ flags) {
    int i = blockIdx.x * blockDim.x + threadIdx.x;
    if (i < BATCH * H) hb[i] = __float2bfloat16(h0[i]);
    if (i < NBLK * FSTRIDE) flags[i] = 0;
}

// ---------------- persistent LSTM: all 512 steps, one kernel ----------------
// 128 blocks x 512 threads (8 waves). Block owns 8 hidden cols (all 4 gates):
// 32 rows of [W_ih | W_hh] (K=1536) LDS-resident for the whole sequence.
// Wave split: wm = wave&3 (16-row batch M-tile), wn = wave>>2 (16-col N-half).
// Step sync: distributed per-block flags (own cache line), relaxed agent atomics,
// NO fences; h exchanged via per-access agent-coherent atomic loads/stores.

__global__ __launch_bounds__(512, 1)
void lstm_persist(const __hip_bfloat16* __restrict__ xb,   // [SEQ][B][INF] bf16
                  const __hip_bfloat16* __restrict__ Wih,  // [4096][512]  bf16
                  const __hip_bfloat16* __restrict__ Whh,  // [4096][1024] bf16
                  const float* __restrict__ bias,          // [4096] f32
                  const float* __restrict__ c0,            // [B][H] f32
                  __hip_bfloat16* __restrict__ hbuf,       // [2][B][H] bf16 (buf0 = h0)
                  int* __restrict__ flags,                 // [NBLK*FSTRIDE] (init 0)
                  float* __restrict__ out)                 // h_seq | hT | cT
{
    __shared__ __align__(16) __hip_bfloat16 Wc[WROWS * WPITCH]; // 98,816 B
    __shared__ float Gs[BATCH][33];                             //  8,448 B

    const int tid   = threadIdx.x;
    const int lane  = tid & 63;
    const int wave  = tid >> 6;       // 0..7
    const int wm    = wave & 3;       // batch m-tile (16 rows)
    const int wn    = wave >> 2;      // N-half (16 of 32 gate rows)
    const int ln15  = lane & 15;
    const int kgrp  = lane >> 4;      // 0..3
    const int j0    = blockIdx.x * NCOL;

    // ---- prologue: stage combined weight rows [Wih(512) | Whh(1024)] ----
    for (int u = tid; u < WROWS * 192; u += 512) {   // 192 short8 per row
        int r    = u / 192;
        int seg  = u - r * 192;                      // 0..191 (16B units)
        int grow = (r >> 3) * H + j0 + (r & 7);
        if (seg < 64) {
            short8 v = *(const short8*)(Wih + (size_t)grow * INF + seg * 8);
            *(short8*)&Wc[r * WPITCH + seg * 8] = v;
        } else {
            short8 v = *(const short8*)(Whh + (size_t)grow * H + (seg - 64) * 8);
            *(short8*)&Wc[r * WPITCH + 512 + (seg - 64) * 8] = v;
        }
    }
    // per-thread elementwise ownership: one (b, j) pair
    const int eb   = tid >> 3;        // batch 0..63
    const int ej   = tid & 7;         // col   0..7
    const int cidx = eb * H + j0 + ej;
    float c_reg = c0[cidx];
    float bias_r[4];
    #pragma unroll
    for (int g = 0; g < 4; ++g) bias_r[g] = bias[g * H + j0 + ej];
    __syncthreads();

    const int arow = wm * 16 + ln15;                 // A-operand batch row
    const __hip_bfloat16* wbase = &Wc[(wn * 16 + ln15) * WPITCH + kgrp * 8];
    float last_h = 0.f;

    for (int t = 0; t < SEQ; ++t) {
        // ---- A. x-part: no h dependence, overlaps other blocks finishing t-1 ----
        const __hip_bfloat16* xrow = xb + ((size_t)t * BATCH + arow) * INF + kgrp * 8;
        float4v acc0 = {0.f, 0.f, 0.f, 0.f};
        float4v acc1 = {0.f, 0.f, 0.f, 0.f};
        #pragma unroll
        for (int ks = 0; ks < 16; ks += 2) {
            short8 af0 = *(const short8*)(xrow + ks * 32);
            short8 bf0 = *(const short8*)(wbase + ks * 32);
            acc0 = __builtin_amdgcn_mfma_f32_16x16x32_bf16(af0, bf0, acc0, 0, 0, 0);
            short8 af1 = *(const short8*)(xrow + (ks + 1) * 32);
            short8 bf1 = *(const short8*)(wbase + (ks + 1) * 32);
            acc1 = __builtin_amdgcn_mfma_f32_16x16x32_bf16(af1, bf1, acc1, 0, 0, 0);
        }

        // ---- B. wait: every block published h(t) (flag >= t). Distributed poll. ----
        if (t > 0) {
            if (tid < NBLK) {
                const int* f = flags + tid * FSTRIDE;
                while (__hip_atomic_load(f, __ATOMIC_RELAXED, __HIP_MEMORY_SCOPE_AGENT) < t) {}
            }
            __syncthreads();
            __builtin_amdgcn_sched_barrier(0);
        }

        // ---- C. h-part: agent-coherent loads (bypass stale L2), all issued up-front ----
        const __hip_bfloat16* hrow =
            hbuf + (size_t)(t & 1) * (BATCH * H) + (size_t)arow * H + kgrp * 8;
        short8 hv[32];
        #pragma unroll
        for (int q = 0; q < 32; ++q) {
            const unsigned int* p = (const unsigned int*)(hrow + q * 32);
            union { unsigned int u[4]; short8 s; } cv;
            cv.u[0] = __hip_atomic_load(p + 0, __ATOMIC_RELAXED, __HIP_MEMORY_SCOPE_AGENT);
            cv.u[1] = __hip_atomic_load(p + 1, __ATOMIC_RELAXED, __HIP_MEMORY_SCOPE_AGENT);
            cv.u[2] = __hip_atomic_load(p + 2, __ATOMIC_RELAXED, __HIP_MEMORY_SCOPE_AGENT);
            cv.u[3] = __hip_atomic_load(p + 3, __ATOMIC_RELAXED, __HIP_MEMORY_SCOPE_AGENT);
            hv[q] = cv.s;
        }
        #pragma unroll
        for (int ks = 0; ks < 32; ks += 2) {
            short8 bf0 = *(const short8*)(wbase + 512 + ks * 32);
            acc0 = __builtin_amdgcn_mfma_f32_16x16x32_bf16(hv[ks], bf0, acc0, 0, 0, 0);
            short8 bf1 = *(const short8*)(wbase + 512 + (ks + 1) * 32);
            acc1 = __builtin_amdgcn_mfma_f32_16x16x32_bf16(hv[ks + 1], bf1, acc1, 0, 0, 0);
        }

        // ---- D. gate exchange. C/D layout: col = lane&15 (n), row = kgrp*4+r (m) ----
        #pragma unroll
        for (int r = 0; r < 4; ++r)
            Gs[wm * 16 + kgrp * 4 + r][wn * 16 + ln15] = acc0[r] + acc1[r];
        __syncthreads();

        // ---- E. elementwise cell update: one (b, j) per thread ----
        float xi = Gs[eb][0 * 8 + ej] + bias_r[0];
        float xf = Gs[eb][1 * 8 + ej] + bias_r[1];
        float xg = Gs[eb][2 * 8 + ej] + bias_r[2];
        float xo = Gs[eb][3 * 8 + ej] + bias_r[3];
        float ig = 1.f / (1.f + __expf(-xi));
        float fg = 1.f / (1.f + __expf(-xf));
        float gg = 2.f / (1.f + __expf(-2.f * xg)) - 1.f;
        float og = 1.f / (1.f + __expf(-xo));
        c_reg = fg * c_reg + ig * gg;
        float th = 2.f / (1.f + __expf(-2.f * c_reg)) - 1.f;
        float h  = og * th;
        last_h   = h;
        out[(size_t)t * (BATCH * H) + cidx] = h;

        // h(t+1) publish: pack bf16 pair across ej-adjacent lanes, agent-coherent store
        union { __hip_bfloat16 b; unsigned short u; } hcv;
        hcv.b = __float2bfloat16(h);
        int nb = __shfl_xor((int)hcv.u, 1, 64);
        if ((ej & 1) == 0) {
            unsigned int pv = (unsigned int)hcv.u | ((unsigned int)(unsigned short)nb << 16);
            unsigned int* dst =
                (unsigned int*)(hbuf + (size_t)((t + 1) & 1) * (BATCH * H) + cidx);
            __hip_atomic_store(dst, pv, __ATOMIC_RELAXED, __HIP_MEMORY_SCOPE_AGENT);
        }
        __syncthreads();   // compiler drains vmcnt here -> h stores at coherent point

        // ---- F. arrive: own flag, own cache line, one relaxed RMW ----
        if (tid == 0)
            __hip_atomic_fetch_add(flags + blockIdx.x * FSTRIDE, 1,
                                   __ATOMIC_RELAXED, __HIP_MEMORY_SCOPE_AGENT);
    }

    // tail: hT, cT
    out[(size_t)SEQ * BATCH * H + cidx]             = last_h;
    out[(size_t)SEQ * BATCH * H + BATCH * H + cidx] = c_reg;
}

// ---------------- launch ----------------

extern "C" void kernel_launch(void* const* d_in, const int* in_sizes, int n_in,
                              void* d_out, int out_size, void* d_ws, size_t ws_size,
                              hipStream_t stream)
{
    const float* x    = (const float*)d_in[0];
    const float* Wih  = (const float*)d_in[1];
    const float* Whh  = (const float*)d_in[2];
    const float* bias = (const float*)d_in[3];
    const float* h0   = (const float*)d_in[4];
    const float* c0   = (const float*)d_in[5];
    float* out = (float*)d_out;

    // workspace layout (bytes), 16B-aligned
    char* ws = (char*)d_ws;
    __hip_bfloat16* xb   = (__hip_bfloat16*)(ws);             // 33,554,432 B
    __hip_bfloat16* Wihb = (__hip_bfloat16*)(ws + 33554432);  //  4,194,304 B
    __hip_bfloat16* Whhb = (__hip_bfloat16*)(ws + 37748736);  //  8,388,608 B
    __hip_bfloat16* hb   = (__hip_bfloat16*)(ws + 46137344);  //    262,144 B (2 x B x H)
    int*            flags= (int*)(ws + 46399488);             //     16,384 B

    f32_to_bf16_k<<<2048, 256, 0, stream>>>(x,   xb,   SEQ * BATCH * INF);
    f32_to_bf16_k<<<512,  256, 0, stream>>>(Wih, Wihb, G4H * INF);
    f32_to_bf16_k<<<1024, 256, 0, stream>>>(Whh, Whhb, G4H * H);
    init_h_k<<<256, 256, 0, stream>>>(h0, hb, flags);

    void* kargs[] = { (void*)&xb, (void*)&Wihb, (void*)&Whhb,
                      (void*)&bias, (void*)&c0, (void*)&hb, (void*)&flags, (void*)&out };
    hipLaunchCooperativeKernel((void*)lstm_persist, dim3(NBLK), dim3(512),
                               kargs, 0, stream);
}

// Round 4
// 6479.218 us; speedup vs baseline: 2.6049x; 2.6049x over previous
//
#include <hip/hip_runtime.h>
#include <hip/hip_bf16.h>

#define SEQ   512
#define BATCH 64
#define INF   512
#define H     1024
#define G4H   4096

#define NBLK    128         // persistent blocks, 1/CU (LDS-bound), co-resident via coop launch
#define NCOL    8           // hidden columns per block
#define WROWS   32          // 4 gates * NCOL weight rows per block
#define WPITCH  1544        // 1536 + 8 bf16 pad (rows 16B-aligned, 2-way banks)
#define FSTRIDE 32          // ints between per-block flags (128B: own cache line)
#define GPITCH  36          // Gs pitch: (4*eb+8g+ej)%32 ~2-way (33 gave 8-way)

typedef short  short8  __attribute__((ext_vector_type(8)));
typedef float  float4v __attribute__((ext_vector_type(4)));

// ---------------- conversion / init kernels ----------------

__global__ void f32_to_bf16_k(const float* __restrict__ src,
                              __hip_bfloat16* __restrict__ dst, int n) {
    int i = blockIdx.x * blockDim.x + threadIdx.x;
    int stride = gridDim.x * blockDim.x;
    for (; i < n; i += stride) dst[i] = __float2bfloat16(src[i]);
}

__global__ void init_h_k(const float* __restrict__ h0, __hip_bfloat16* __restrict__ hb,
                         int* __restrict__ flags) {
    int i = blockIdx.x * blockDim.x + threadIdx.x;
    if (i < BATCH * H) hb[i] = __float2bfloat16(h0[i]);
    if (i < NBLK * FSTRIDE) flags[i] = 0;
}

// ---------------- persistent LSTM: all 512 steps, one kernel ----------------
// 128 blocks x 512 threads (8 waves). Block owns 8 hidden cols (all 4 gates):
// 32 rows of [W_ih | W_hh] (K=1536) LDS-resident for the whole sequence.
// Wave split: wm = wave&3 (16-row batch M-tile), wn = wave>>2 (16-col N-half).
// Sync: per-block flags (own line, agent atomic store / poll with s_sleep).
// h exchange: packed agent atomic stores (write-through) + batched inline-asm
// sc0/sc1 dwordx4 loads (L2-bypass) -> no fences, x stays L2-resident.

__global__ __launch_bounds__(512, 1)
void lstm_persist(const __hip_bfloat16* __restrict__ xb,   // [SEQ][B][INF] bf16
                  const __hip_bfloat16* __restrict__ Wih,  // [4096][512]  bf16
                  const __hip_bfloat16* __restrict__ Whh,  // [4096][1024] bf16
                  const float* __restrict__ bias,          // [4096] f32
                  const float* __restrict__ c0,            // [B][H] f32
                  __hip_bfloat16* __restrict__ hbuf,       // [2][B][H] bf16 (buf0 = h0)
                  int* __restrict__ flags,                 // [NBLK*FSTRIDE] (init 0)
                  float* __restrict__ out)                 // h_seq | hT | cT
{
    __shared__ __align__(16) __hip_bfloat16 Wc[WROWS * WPITCH]; // 98,816 B
    __shared__ float Gs[BATCH][GPITCH];                         //  9,216 B

    const int tid   = threadIdx.x;
    const int lane  = tid & 63;
    const int wave  = tid >> 6;       // 0..7
    const int wm    = wave & 3;       // batch m-tile (16 rows)
    const int wn    = wave >> 2;      // N-half (16 of 32 gate rows)
    const int ln15  = lane & 15;
    const int kgrp  = lane >> 4;      // 0..3
    const int j0    = blockIdx.x * NCOL;

    // ---- prologue: stage combined weight rows [Wih(512) | Whh(1024)] ----
    for (int u = tid; u < WROWS * 192; u += 512) {   // 192 short8 per row
        int r    = u / 192;
        int seg  = u - r * 192;                      // 0..191 (16B units)
        int grow = (r >> 3) * H + j0 + (r & 7);
        if (seg < 64) {
            short8 v = *(const short8*)(Wih + (size_t)grow * INF + seg * 8);
            *(short8*)&Wc[r * WPITCH + seg * 8] = v;
        } else {
            short8 v = *(const short8*)(Whh + (size_t)grow * H + (seg - 64) * 8);
            *(short8*)&Wc[r * WPITCH + 512 + (seg - 64) * 8] = v;
        }
    }
    // per-thread elementwise ownership: one (b, j) pair
    const int eb   = tid >> 3;        // batch 0..63
    const int ej   = tid & 7;         // col   0..7
    const int cidx = eb * H + j0 + ej;
    float c_reg = c0[cidx];
    float bias_r[4];
    #pragma unroll
    for (int g = 0; g < 4; ++g) bias_r[g] = bias[g * H + j0 + ej];
    __syncthreads();

    const int arow = wm * 16 + ln15;                 // A-operand batch row
    const __hip_bfloat16* wbase = &Wc[(wn * 16 + ln15) * WPITCH + kgrp * 8];
    float last_h = 0.f;

    for (int t = 0; t < SEQ; ++t) {
        // ---- A. x-part: no h dependence, overlaps other blocks finishing t-1 ----
        const __hip_bfloat16* xrow = xb + ((size_t)t * BATCH + arow) * INF + kgrp * 8;
        float4v acc0 = {0.f, 0.f, 0.f, 0.f};
        float4v acc1 = {0.f, 0.f, 0.f, 0.f};
        #pragma unroll
        for (int ks = 0; ks < 16; ks += 2) {
            short8 af0 = *(const short8*)(xrow + ks * 32);
            short8 bf0 = *(const short8*)(wbase + ks * 32);
            acc0 = __builtin_amdgcn_mfma_f32_16x16x32_bf16(af0, bf0, acc0, 0, 0, 0);
            short8 af1 = *(const short8*)(xrow + (ks + 1) * 32);
            short8 bf1 = *(const short8*)(wbase + (ks + 1) * 32);
            acc1 = __builtin_amdgcn_mfma_f32_16x16x32_bf16(af1, bf1, acc1, 0, 0, 0);
        }

        // ---- B. wait: every block published h(t) (flag >= t). Distributed poll. ----
        if (t > 0) {
            if (tid < NBLK) {
                const int* f = flags + tid * FSTRIDE;
                while (__hip_atomic_load(f, __ATOMIC_RELAXED, __HIP_MEMORY_SCOPE_AGENT) < t)
                    __builtin_amdgcn_s_sleep(1);
            }
            __syncthreads();
            __builtin_amdgcn_sched_barrier(0);
        }

        // ---- C. h-part: batched coherent vector loads (bypass L2), then MFMAs ----
        const __hip_bfloat16* hrow =
            hbuf + (size_t)(t & 1) * (BATCH * H) + (size_t)arow * H + kgrp * 8;
        short8 hv[32];
        #pragma unroll
        for (int q = 0; q < 32; ++q) {
            asm volatile("global_load_dwordx4 %0, %1, off offset:%2 sc0 sc1"
                         : "=&v"(hv[q])
                         : "v"(hrow), "i"(q * 64));
        }
        asm volatile("s_waitcnt vmcnt(0)" ::: "memory");
        __builtin_amdgcn_sched_barrier(0);
        #pragma unroll
        for (int ks = 0; ks < 32; ks += 2) {
            short8 bf0 = *(const short8*)(wbase + 512 + ks * 32);
            acc0 = __builtin_amdgcn_mfma_f32_16x16x32_bf16(hv[ks], bf0, acc0, 0, 0, 0);
            short8 bf1 = *(const short8*)(wbase + 512 + (ks + 1) * 32);
            acc1 = __builtin_amdgcn_mfma_f32_16x16x32_bf16(hv[ks + 1], bf1, acc1, 0, 0, 0);
        }

        // ---- D. gate exchange. C/D layout: col = lane&15 (n), row = kgrp*4+r (m) ----
        #pragma unroll
        for (int r = 0; r < 4; ++r)
            Gs[wm * 16 + kgrp * 4 + r][wn * 16 + ln15] = acc0[r] + acc1[r];
        __syncthreads();

        // ---- E. elementwise cell update: one (b, j) per thread ----
        float xi = Gs[eb][0 * 8 + ej] + bias_r[0];
        float xf = Gs[eb][1 * 8 + ej] + bias_r[1];
        float xg = Gs[eb][2 * 8 + ej] + bias_r[2];
        float xo = Gs[eb][3 * 8 + ej] + bias_r[3];
        float ig = 1.f / (1.f + __expf(-xi));
        float fg = 1.f / (1.f + __expf(-xf));
        float gg = 2.f / (1.f + __expf(-2.f * xg)) - 1.f;
        float og = 1.f / (1.f + __expf(-xo));
        c_reg = fg * c_reg + ig * gg;
        float th = 2.f / (1.f + __expf(-2.f * c_reg)) - 1.f;
        float h  = og * th;
        last_h   = h;

        // h(t+1) publish first (critical path): pack bf16 pair across ej-adjacent
        // lanes, agent-coherent store (write-through to L3)
        union { __hip_bfloat16 b; unsigned short u; } hcv;
        hcv.b = __float2bfloat16(h);
        int nb = __shfl_xor((int)hcv.u, 1, 64);
        if ((ej & 1) == 0) {
            unsigned int pv = (unsigned int)hcv.u | ((unsigned int)(unsigned short)nb << 16);
            unsigned int* dst =
                (unsigned int*)(hbuf + (size_t)((t + 1) & 1) * (BATCH * H) + cidx);
            __hip_atomic_store(dst, pv, __ATOMIC_RELAXED, __HIP_MEMORY_SCOPE_AGENT);
        }
        __syncthreads();   // drains vmcnt in every wave -> h stores at L3

        // ---- F. arrive: own flag, own line, plain agent store (no RMW) ----
        if (tid == 0)
            __hip_atomic_store(flags + blockIdx.x * FSTRIDE, t + 1,
                               __ATOMIC_RELAXED, __HIP_MEMORY_SCOPE_AGENT);

        // ---- G. h_seq write: off the recurrence critical path ----
        out[(size_t)t * (BATCH * H) + cidx] = h;
    }

    // tail: hT, cT
    out[(size_t)SEQ * BATCH * H + cidx]             = last_h;
    out[(size_t)SEQ * BATCH * H + BATCH * H + cidx] = c_reg;
}

// ---------------- launch ----------------

extern "C" void kernel_launch(void* const* d_in, const int* in_sizes, int n_in,
                              void* d_out, int out_size, void* d_ws, size_t ws_size,
                              hipStream_t stream)
{
    const float* x    = (const float*)d_in[0];
    const float* Wih  = (const float*)d_in[1];
    const float* Whh  = (const float*)d_in[2];
    const float* bias = (const float*)d_in[3];
    const float* h0   = (const float*)d_in[4];
    const float* c0   = (const float*)d_in[5];
    float* out = (float*)d_out;

    // workspace layout (bytes), 16B-aligned
    char* ws = (char*)d_ws;
    __hip_bfloat16* xb   = (__hip_bfloat16*)(ws);             // 33,554,432 B
    __hip_bfloat16* Wihb = (__hip_bfloat16*)(ws + 33554432);  //  4,194,304 B
    __hip_bfloat16* Whhb = (__hip_bfloat16*)(ws + 37748736);  //  8,388,608 B
    __hip_bfloat16* hb   = (__hip_bfloat16*)(ws + 46137344);  //    262,144 B (2 x B x H)
    int*            flags= (int*)(ws + 46399488);             //     16,384 B

    f32_to_bf16_k<<<2048, 256, 0, stream>>>(x,   xb,   SEQ * BATCH * INF);
    f32_to_bf16_k<<<512,  256, 0, stream>>>(Wih, Wihb, G4H * INF);
    f32_to_bf16_k<<<1024, 256, 0, stream>>>(Whh, Whhb, G4H * H);
    init_h_k<<<256, 256, 0, stream>>>(h0, hb, flags);

    void* kargs[] = { (void*)&xb, (void*)&Wihb, (void*)&Whhb,
                      (void*)&bias, (void*)&c0, (void*)&hb, (void*)&flags, (void*)&out };
    hipLaunchCooperativeKernel((void*)lstm_persist, dim3(NBLK), dim3(512),
                               kargs, 0, stream);
}

// Round 6
// 3752.604 us; speedup vs baseline: 4.4976x; 1.7266x over previous
//
#include <hip/hip_runtime.h>
#include <hip/hip_bf16.h>

#define SEQ   512
#define BATCH 64
#define INF   512
#define H     1024
#define G4H   4096

#define NBLK    128         // persistent blocks, co-resident via coop launch
#define NCOL    8           // hidden columns per block
#define FSTRIDE 32          // ints between per-block flags (128B: own cache line)
#define WSP     520         // x-weight LDS pitch (512 + 8 bf16)

typedef short  short8  __attribute__((ext_vector_type(8)));
typedef float  float4v __attribute__((ext_vector_type(4)));
typedef int    int4v   __attribute__((ext_vector_type(4)));

// ---------------- conversion / init kernels ----------------

__global__ void f32_to_bf16_k(const float* __restrict__ src,
                              __hip_bfloat16* __restrict__ dst, int n) {
    int i = blockIdx.x * blockDim.x + threadIdx.x;
    int stride = gridDim.x * blockDim.x;
    for (; i < n; i += stride) dst[i] = __float2bfloat16(src[i]);
}

__global__ void init_h_k(const float* __restrict__ h0, __hip_bfloat16* __restrict__ hb,
                         int* __restrict__ flags) {
    int i = blockIdx.x * blockDim.x + threadIdx.x;
    if (i < BATCH * H) hb[i] = __float2bfloat16(h0[i]);
    if (i < NBLK * FSTRIDE) flags[i] = 0;
}

// ---------------- persistent LSTM: all 512 steps, one kernel ----------------
// 128 blocks x 512 threads (8 waves). Block owns 8 hidden cols (all 4 gates).
// Wave = (mh: 32-batch half) x (q: 256-wide h-K-quarter + 128-wide x-K-quarter).
// h-weights (2 n-tiles x 8 ksteps = 64 VGPR) live in registers all 512 steps.
// x-weights (32 rows x 512) live in LDS; x-part runs pre-barrier (overlap).
// Peak live VGPR ~190 < 256 cap for a 512-thread block (2 waves/SIMD).
// Sync: per-block flags (own line, relaxed agent atomics, proven R3/R4).
// h exchange: packed dwordx4 sc0/sc1 write-through stores + batched sc0/sc1
// dwordx4 loads (one L3 round trip) -> no fences, x stays L2-resident.

__global__ __launch_bounds__(512, 2)
void lstm_persist(const __hip_bfloat16* __restrict__ xb,   // [SEQ][B][INF] bf16
                  const __hip_bfloat16* __restrict__ Wih,  // [4096][512]  bf16
                  const __hip_bfloat16* __restrict__ Whh,  // [4096][1024] bf16
                  const float* __restrict__ bias,          // [4096] f32
                  const float* __restrict__ c0,            // [B][H] f32
                  __hip_bfloat16* __restrict__ hbuf,       // [2][B][H] bf16 (buf0 = h0)
                  int* __restrict__ flags,                 // [NBLK*FSTRIDE] (init 0)
                  float* __restrict__ out)                 // h_seq | hT | cT
{
    __shared__ __align__(16) __hip_bfloat16 Ws[32][WSP];  // x-weights, 33,280 B
    __shared__ float Gs[32][4][64];                       // [n][q][b^], 32,768 B

    const int tid   = threadIdx.x;
    const int lane  = tid & 63;
    const int wave  = tid >> 6;       // 0..7
    const int mh    = wave >> 2;      // batch half (32 rows)
    const int q     = wave & 3;       // K-quarter
    const int ln15  = lane & 15;
    const int kgrp  = lane >> 4;      // 0..3
    const int j0    = blockIdx.x * NCOL;

    // ---- prologue 1: x-weights -> LDS (32 rows x 512, once) ----
    #pragma unroll
    for (int v = 0; v < 4; ++v) {
        int u   = v * 512 + tid;      // 2048 16B units
        int row = u >> 6;
        int c16 = u & 63;
        int grow = (row >> 3) * H + j0 + (row & 7);
        short8 w = *(const short8*)(Wih + (size_t)grow * INF + c16 * 8);
        *(short8*)&Ws[row][c16 * 8] = w;
    }
    // ---- prologue 2: h-weights -> registers (persistent, 64 VGPR) ----
    // frag (nt, ks): row r = nt*16+ln15 -> gate g=r>>3, col j0+(r&7);
    // h col = q*256 + ks*32 + kgrp*8
    short8 whf[2][8];
    #pragma unroll
    for (int nt = 0; nt < 2; ++nt) {
        int r    = nt * 16 + ln15;
        int grow = (r >> 3) * H + j0 + (r & 7);
        #pragma unroll
        for (int ks = 0; ks < 8; ++ks)
            whf[nt][ks] = *(const short8*)(Whh + (size_t)grow * H + q * 256 + ks * 32 + kgrp * 8);
    }

    // per-thread elementwise ownership: one (b, j) pair
    const int eb   = tid >> 3;        // batch 0..63
    const int ej   = tid & 7;         // col   0..7
    const int cidx = eb * H + j0 + ej;
    float c_reg = c0[cidx];
    float bias_r[4];
    #pragma unroll
    for (int g = 0; g < 4; ++g) bias_r[g] = bias[g * H + j0 + ej];

    const int arow0 = mh * 32 + ln15;     // A batch row (second m-tile adds 16)
    const int bsw_w = (ln15 & 7) << 3;    // write-side b swizzle
    const int bswr  = eb ^ (ej << 3);     // read-side swizzled b
    __syncthreads();

    float last_h = 0.f;

    for (int t = 0; t < SEQ; ++t) {
        float4v acc[2][2];
        #pragma unroll
        for (int mt = 0; mt < 2; ++mt)
            #pragma unroll
            for (int nt = 0; nt < 2; ++nt)
                acc[mt][nt] = (float4v){0.f, 0.f, 0.f, 0.f};

        // ---- A. x-part (128-wide K-quarter): pre-barrier, overlaps skew ----
        {
            const __hip_bfloat16* xB = xb + (size_t)t * BATCH * INF;
            #pragma unroll
            for (int ks = 0; ks < 4; ++ks) {
                int xc = q * 128 + ks * 32 + kgrp * 8;
                short8 a0 = *(const short8*)(xB + (size_t)arow0 * INF + xc);
                short8 a1 = *(const short8*)(xB + (size_t)(arow0 + 16) * INF + xc);
                short8 w0 = *(const short8*)&Ws[ln15][xc];
                short8 w1 = *(const short8*)&Ws[16 + ln15][xc];
                acc[0][0] = __builtin_amdgcn_mfma_f32_16x16x32_bf16(a0, w0, acc[0][0], 0, 0, 0);
                acc[0][1] = __builtin_amdgcn_mfma_f32_16x16x32_bf16(a0, w1, acc[0][1], 0, 0, 0);
                acc[1][0] = __builtin_amdgcn_mfma_f32_16x16x32_bf16(a1, w0, acc[1][0], 0, 0, 0);
                acc[1][1] = __builtin_amdgcn_mfma_f32_16x16x32_bf16(a1, w1, acc[1][1], 0, 0, 0);
            }
        }

        // ---- B. wait: every block published h(t). Distributed per-line polls. ----
        if (t > 0) {
            if (tid < NBLK) {
                const int* f = flags + tid * FSTRIDE;
                while (__hip_atomic_load(f, __ATOMIC_RELAXED, __HIP_MEMORY_SCOPE_AGENT) < t)
                    __builtin_amdgcn_s_sleep(1);
            }
            __syncthreads();
            __builtin_amdgcn_sched_barrier(0);
        }

        // ---- C. h-part: batch-issue 16 coherent loads (one L3 RTT), then MFMAs ----
        {
            const __hip_bfloat16* hB  = hbuf + (size_t)(t & 1) * (BATCH * H);
            const __hip_bfloat16* h0p = hB + (size_t)arow0 * H + q * 256 + kgrp * 8;
            const __hip_bfloat16* h1p = h0p + (size_t)16 * H;
            short8 av0[8], av1[8];
            #pragma unroll
            for (int ks = 0; ks < 8; ++ks)
                asm volatile("global_load_dwordx4 %0, %1, off offset:%2 sc0 sc1"
                             : "=&v"(av0[ks]) : "v"(h0p), "i"(ks * 64));
            #pragma unroll
            for (int ks = 0; ks < 8; ++ks)
                asm volatile("global_load_dwordx4 %0, %1, off offset:%2 sc0 sc1"
                             : "=&v"(av1[ks]) : "v"(h1p), "i"(ks * 64));
            asm volatile("s_waitcnt vmcnt(0)" ::: "memory");
            __builtin_amdgcn_sched_barrier(0);
            #pragma unroll
            for (int ks = 0; ks < 8; ++ks) {
                acc[0][0] = __builtin_amdgcn_mfma_f32_16x16x32_bf16(av0[ks], whf[0][ks], acc[0][0], 0, 0, 0);
                acc[0][1] = __builtin_amdgcn_mfma_f32_16x16x32_bf16(av0[ks], whf[1][ks], acc[0][1], 0, 0, 0);
                acc[1][0] = __builtin_amdgcn_mfma_f32_16x16x32_bf16(av1[ks], whf[0][ks], acc[1][0], 0, 0, 0);
                acc[1][1] = __builtin_amdgcn_mfma_f32_16x16x32_bf16(av1[ks], whf[1][ks], acc[1][1], 0, 0, 0);
            }
        }

        // ---- D. exchange: acc -> Gs[n][q][b^swz]. C/D: col=lane&15 (n),
        //      row = kgrp*4+r within m-tile (batch).
        #pragma unroll
        for (int mt = 0; mt < 2; ++mt) {
            #pragma unroll
            for (int nt = 0; nt < 2; ++nt) {
                int n  = nt * 16 + ln15;
                int bb = mh * 32 + mt * 16 + kgrp * 4;
                #pragma unroll
                for (int r = 0; r < 4; ++r)
                    Gs[n][q][(bb + r) ^ bsw_w] = acc[mt][nt][r];
            }
        }
        __syncthreads();

        // ---- E. cell update: one (b, j) per thread; sum 4 K-quarter partials ----
        float gate[4];
        #pragma unroll
        for (int g = 0; g < 4; ++g) {
            int n = g * 8 + ej;
            gate[g] = Gs[n][0][bswr] + Gs[n][1][bswr] +
                      Gs[n][2][bswr] + Gs[n][3][bswr] + bias_r[g];
        }
        float ig = 1.f / (1.f + __expf(-gate[0]));
        float fg = 1.f / (1.f + __expf(-gate[1]));
        float gg = 2.f / (1.f + __expf(-2.f * gate[2])) - 1.f;
        float og = 1.f / (1.f + __expf(-gate[3]));
        c_reg = fg * c_reg + ig * gg;
        float th = 2.f / (1.f + __expf(-2.f * c_reg)) - 1.f;
        float h  = og * th;
        last_h   = h;

        // h(t+1) publish: gather 8 bf16 of this row into ej==0 lane (4 shfls),
        // one dwordx4 write-through store per row (64 stores/block).
        union { __hip_bfloat16 b; unsigned short u; } hcv;
        hcv.b = __float2bfloat16(h);
        int me = (int)hcv.u;
        int pr = __shfl_xor(me, 1, 64);
        unsigned int vlo = (ej & 1) ? (unsigned int)(unsigned short)pr : (unsigned int)(unsigned short)me;
        unsigned int vhi = (ej & 1) ? (unsigned int)(unsigned short)me : (unsigned int)(unsigned short)pr;
        int a  = (int)(vlo | (vhi << 16));
        int b2 = __shfl_xor(a, 2, 64);
        int c4 = __shfl_xor(a, 4, 64);
        int d6 = __shfl_xor(b2, 4, 64);
        if (ej == 0) {
            int4v v4 = {a, b2, c4, d6};
            __hip_bfloat16* dst = hbuf + (size_t)((t + 1) & 1) * (BATCH * H)
                                       + (size_t)eb * H + j0;
            asm volatile("global_store_dwordx4 %0, %1, off sc0 sc1"
                         :: "v"(dst), "v"(v4) : "memory");
        }
        out[(size_t)t * (BATCH * H) + cidx] = h;   // h_seq (off critical path)
        __syncthreads();   // drains vmcnt in every wave -> h stores at L3

        // ---- F. arrive: own flag, own line, plain agent store ----
        if (tid == 0)
            __hip_atomic_store(flags + blockIdx.x * FSTRIDE, t + 1,
                               __ATOMIC_RELAXED, __HIP_MEMORY_SCOPE_AGENT);
    }

    // tail: hT, cT
    out[(size_t)SEQ * BATCH * H + cidx]             = last_h;
    out[(size_t)SEQ * BATCH * H + BATCH * H + cidx] = c_reg;
}

// ---------------- launch ----------------

extern "C" void kernel_launch(void* const* d_in, const int* in_sizes, int n_in,
                              void* d_out, int out_size, void* d_ws, size_t ws_size,
                              hipStream_t stream)
{
    const float* x    = (const float*)d_in[0];
    const float* Wih  = (const float*)d_in[1];
    const float* Whh  = (const float*)d_in[2];
    const float* bias = (const float*)d_in[3];
    const float* h0   = (const float*)d_in[4];
    const float* c0   = (const float*)d_in[5];
    float* out = (float*)d_out;

    // workspace layout (bytes), 16B-aligned
    char* ws = (char*)d_ws;
    __hip_bfloat16* xb   = (__hip_bfloat16*)(ws);             // 33,554,432 B
    __hip_bfloat16* Wihb = (__hip_bfloat16*)(ws + 33554432);  //  4,194,304 B
    __hip_bfloat16* Whhb = (__hip_bfloat16*)(ws + 37748736);  //  8,388,608 B
    __hip_bfloat16* hb   = (__hip_bfloat16*)(ws + 46137344);  //    262,144 B (2 x B x H)
    int*            flags= (int*)(ws + 46399488);             //     16,384 B

    f32_to_bf16_k<<<2048, 256, 0, stream>>>(x,   xb,   SEQ * BATCH * INF);
    f32_to_bf16_k<<<512,  256, 0, stream>>>(Wih, Wihb, G4H * INF);
    f32_to_bf16_k<<<1024, 256, 0, stream>>>(Whh, Whhb, G4H * H);
    init_h_k<<<256, 256, 0, stream>>>(h0, hb, flags);

    void* kargs[] = { (void*)&xb, (void*)&Wihb, (void*)&Whhb,
                      (void*)&bias, (void*)&c0, (void*)&hb, (void*)&flags, (void*)&out };
    hipLaunchCooperativeKernel((void*)lstm_persist, dim3(NBLK), dim3(512),
                               kargs, 0, stream);
}